// Round 1
// baseline (1384.834 us; speedup 1.0000x reference)
//
#include <hip/hip_runtime.h>
#include <math.h>

// ---------------------------------------------------------------------------
// FancyNet: 4-level hierarchical GNN + MLP head on MI355X.
//   * hW = h @ W_msg per-node (gather commutes with matmul) -> 7x less GEMM
//   * up_l == arange(N_l/2) => downsample = first-half rows; ".at[up].set(hud)"
//     = conditional-source read (j<half ? top : old)
//   * propagation unrolled to 10 prop kernels with ping-pong buffers
//   * BN folds to scale/shift; bn2 folded into Wc' + bias13
//   * R1 fix: NO contended global float atomics -- stats kernels write
//     per-block partials; finalize kernels reduce them.
//   * R2 fix: CSR build rewritten as a two-level counting sort (binned).
//     Old k_scatter_all wrote col[] in random slot order: 1.72M x 4B scattered
//     writes -> 110MB of 64B-line write-backs at 11% HBM efficiency (133us).
//     New path: bin edges by dst>>10 (240 bins = blk_level map), scatter packed
//     (i_local,j) into bin-grouped segments (dense appends -> full lines), then
//     one WG per bin builds rp (coalesced int4) + col (28KB L2-resident region)
//     with LDS counts/scan/cursors. Replicated cursors (16/bin) keep
//     same-address atomic chains ~450 deep (R1 lesson: 2048-deep = 162us).
// ---------------------------------------------------------------------------

#define HID 80
constexpr int cN0 = 131072;

__device__ __forceinline__ float eluf(float x) { return x > 0.f ? x : expm1f(x); }

// ---------------- bn1 stats (6 cols): 2 rows/thread as 3x float4, block partials ----------------
__global__ void k_bn1_stats(const float* __restrict__ feat, float* __restrict__ pacc) {
  float s[6] = {0,0,0,0,0,0}, q[6] = {0,0,0,0,0,0};
  int idx = blockIdx.x * blockDim.x + threadIdx.x;
  int stride = gridDim.x * blockDim.x;
  for (int r2 = idx; r2 < cN0 / 2; r2 += stride) {
    const float4* p = (const float4*)(feat + (size_t)r2 * 12);
    float4 a = p[0], b = p[1], c = p[2];
    s[0] += a.x + b.z;  q[0] += a.x*a.x + b.z*b.z;
    s[1] += a.y + b.w;  q[1] += a.y*a.y + b.w*b.w;
    s[2] += a.z + c.x;  q[2] += a.z*a.z + c.x*c.x;
    s[3] += a.w + c.y;  q[3] += a.w*a.w + c.y*c.y;
    s[4] += b.x + c.z;  q[4] += b.x*b.x + c.z*c.z;
    s[5] += b.y + c.w;  q[5] += b.y*b.y + c.w*c.w;
  }
#pragma unroll
  for (int k = 0; k < 6; k++) {
    for (int off = 32; off; off >>= 1) {
      s[k] += __shfl_down(s[k], off, 64);
      q[k] += __shfl_down(q[k], off, 64);
    }
  }
  __shared__ float ls[4][12];
  int wid = threadIdx.x >> 6;
  if ((threadIdx.x & 63) == 0) {
#pragma unroll
    for (int k = 0; k < 6; k++) { ls[wid][k] = s[k]; ls[wid][6 + k] = q[k]; }
  }
  __syncthreads();
  if (threadIdx.x < 12) {
    pacc[blockIdx.x * 12 + threadIdx.x] =
        ls[0][threadIdx.x] + ls[1][threadIdx.x] + ls[2][threadIdx.x] + ls[3][threadIdx.x];
  }
}

// ---------------- finalize per-channel scale/shift from npart block partials ----------------
__global__ void k_finalize(const float* __restrict__ pacc, int npart,
                           const float* __restrict__ g, const float* __restrict__ b,
                           float* __restrict__ ss, int ncols, float inv_n) {
  int c = threadIdx.x;
  if (c >= ncols) return;
  float s = 0.f, q = 0.f;
  for (int p = 0; p < npart; p++) {
    s += pacc[p * 2 * ncols + c];
    q += pacc[p * 2 * ncols + ncols + c];
  }
  float m = s * inv_n;
  float v = q * inv_n - m * m;
  float sc = g[c] * rsqrtf(v + 1e-5f);
  ss[c] = sc;
  ss[ncols + c] = b[c] - m * sc;
}

// ---------------- embedding: t = bn1(feat) @ W_emb  (6 -> 80) ----------------
__global__ void k_emb4(const float* __restrict__ feat, const float* __restrict__ Wemb,
                       const float* __restrict__ ss, float* __restrict__ t) {
  __shared__ float Wl[6 * HID];
  __shared__ float sc[12];
  for (int i = threadIdx.x; i < 6 * HID; i += blockDim.x) Wl[i] = Wemb[i];
  if (threadIdx.x < 12) sc[threadIdx.x] = ss[threadIdx.x];
  __syncthreads();
  int gid = blockIdx.x * blockDim.x + threadIdx.x;
  if (gid >= cN0 * (HID/4)) return;
  int r = gid / (HID/4);
  int c4 = (gid - r * (HID/4)) * 4;
  float a[6];
#pragma unroll
  for (int k = 0; k < 6; k++) a[k] = feat[r*6 + k] * sc[k] + sc[6 + k];
  float4 o;
  float* op = (float*)&o;
#pragma unroll
  for (int i = 0; i < 4; i++) {
    float v = 0.f;
#pragma unroll
    for (int k = 0; k < 6; k++) v += a[k] * Wl[k*HID + c4 + i];
    op[i] = v;
  }
  *(float4*)(t + (size_t)r*HID + c4) = o;
}

// ---------------- column stats -> per-block partials (LDS atomics only) ----------------
__global__ void k_colstats(const float* __restrict__ x, int nrows, int ncols,
                           float* __restrict__ pacc) {
  extern __shared__ float ls[]; // 2*ncols
  int c = threadIdx.x % ncols;
  int sub = threadIdx.x / ncols;
  int rows_per = blockDim.x / ncols;
  for (int i = threadIdx.x; i < 2*ncols; i += blockDim.x) ls[i] = 0.f;
  __syncthreads();
  float s = 0.f, q = 0.f;
  for (int r = blockIdx.x * rows_per + sub; r < nrows; r += gridDim.x * rows_per) {
    float v = x[(size_t)r * ncols + c];
    s += v; q += v*v;
  }
  atomicAdd(&ls[c], s);
  atomicAdd(&ls[ncols + c], q);
  __syncthreads();
  for (int i = threadIdx.x; i < 2*ncols; i += blockDim.x)
    pacc[blockIdx.x * 2 * ncols + i] = ls[i];
}

// ---------------- in-place scale+shift+relu over 80-col matrix ----------------
__global__ void k_scale_relu4(float* __restrict__ x, const float* __restrict__ ss, int ntot4) {
  int gid = blockIdx.x * blockDim.x + threadIdx.x;
  if (gid >= ntot4) return;
  int r = gid / (HID/4);
  int c4 = (gid - r * (HID/4)) * 4;
  float4 t = *(float4*)(x + (size_t)r*HID + c4);
  float* tp = (float*)&t;
#pragma unroll
  for (int i = 0; i < 4; i++) {
    float v = tp[i] * ss[c4 + i] + ss[HID + c4 + i];
    tp[i] = v > 0.f ? v : 0.f;
  }
  *(float4*)(x + (size_t)r*HID + c4) = t;
}

// ---------------- binned CSR build ----------------
// Bins: 1024 dst nodes each. Level bin counts {128,64,32,16} -> 240 bins total.
// REPS cursor replicas per bin (rep = wgId & 15) bound same-address atomic depth.
#define REPS 16
#define NBINS 240
#define NEDGE_TOT 1720320
#define BIN_CHUNK 2048   // edges per workgroup in binA/binB; 1720320/2048 = 840 exact

struct BinP {
  const int* ii[4]; const int* jj[4];
  int* cnt;     // [NBINS*REPS] per-(bin,rep) edge counts
  int* bstart;  // [NBINS*REPS+1] exclusive scan of cnt
  int* bcur;    // [NBINS*REPS] working cursors for binB
  int* pairs;   // [NEDGE_TOT] packed (i_local<<17 | j), bin-grouped
  int* rp[4]; int* col[4];
};

__device__ __forceinline__ int edge_level(int gid, int& el) {
  if (gid < 917504)  { el = gid;           return 0; }
  if (gid < 1376256) { el = gid - 917504;  return 1; }
  if (gid < 1605632) { el = gid - 1376256; return 2; }
  el = gid - 1605632; return 3;
}
__device__ __forceinline__ int blk_level(int b, int& lb) {
  if (b < 128) { lb = b;       return 0; }
  if (b < 192) { lb = b - 128; return 1; }
  if (b < 224) { lb = b - 192; return 2; }
  lb = b - 224; return 3;
}
__constant__ const int cNN[4] = {131072, 65536, 32768, 16384};
__constant__ const int cNE[4] = {917504, 458752, 229376, 114688};
__constant__ const int cNB[4] = {128, 64, 32, 16};
__constant__ const int cLB[4] = {0, 128, 192, 224};   // first bin of each level

// Pass A: per-WG LDS histogram over 240 bins, flush to global (bin,rep) counters.
__global__ void k_binA(BinP p) {
  __shared__ int h[NBINS];
  for (int i = threadIdx.x; i < NBINS; i += 256) h[i] = 0;
  __syncthreads();
  int base = blockIdx.x * BIN_CHUNK;
#pragma unroll
  for (int it = 0; it < BIN_CHUNK / 256; it++) {
    int e = base + it * 256 + threadIdx.x;
    int el; int l = edge_level(e, el);
    int b = cLB[l] + (p.ii[l][el] >> 10);
    atomicAdd(&h[b], 1);
  }
  __syncthreads();
  int rep = blockIdx.x & (REPS - 1);
  for (int i = threadIdx.x; i < NBINS; i += 256)
    if (h[i]) atomicAdd(&p.cnt[i * REPS + rep], h[i]);
}

// Pass B scan: one WG, exclusive scan of 3840 counters (256 threads x 15 each).
__global__ void k_binScan(BinP p) {
  __shared__ int sd[256];
  int t = threadIdx.x;
  int v[15];
  int s = 0;
#pragma unroll
  for (int k = 0; k < 15; k++) { v[k] = p.cnt[t * 15 + k]; s += v[k]; }
  sd[t] = s;
  __syncthreads();
  for (int off = 1; off < 256; off <<= 1) {
    int x = sd[t];
    if (t >= off) x += sd[t - off];
    __syncthreads();
    sd[t] = x;
    __syncthreads();
  }
  int pre = sd[t] - s;   // exclusive prefix of this thread's 15-run
#pragma unroll
  for (int k = 0; k < 15; k++) {
    p.bstart[t * 15 + k] = pre;
    p.bcur[t * 15 + k] = pre;
    pre += v[k];
  }
  if (t == 255) p.bstart[NBINS * REPS] = pre;   // == NEDGE_TOT
}

// Pass C: scatter packed (i_local,j) into bin-grouped segments. Same WG->edge
// partition and rep mapping as binA, so per-(bin,rep) counts match exactly.
// Dense per-segment appends -> L2 merges lines -> ~1x write amplification.
__global__ void k_binB(BinP p) {
  int base = blockIdx.x * BIN_CHUNK;
  int rep = blockIdx.x & (REPS - 1);
#pragma unroll
  for (int it = 0; it < BIN_CHUNK / 256; it++) {
    int e = base + it * 256 + threadIdx.x;
    int el; int l = edge_level(e, el);
    int i = p.ii[l][el], j = p.jj[l][el];
    int b = cLB[l] + (i >> 10);
    int pos = atomicAdd(&p.bcur[b * REPS + rep], 1);
    p.pairs[pos] = ((i & 1023) << 17) | j;   // j < 131072 -> 17 bits
  }
}

// Pass D: one WG per bin. LDS degree count + scan -> rp (coalesced int4),
// LDS cursors -> col scatter confined to this bin's contiguous ~28KB region.
__global__ void __launch_bounds__(256) k_binCSR(BinP p) {
  __shared__ int d[1024];
  __shared__ int sd[256];
  int lb; int l = blk_level(blockIdx.x, lb);
  int t = threadIdx.x;
  int e0g = p.bstart[blockIdx.x * REPS];
  int e1g = p.bstart[(blockIdx.x + 1) * REPS];
  int lvlbase = p.bstart[cLB[l] * REPS];
  int e0 = e0g - lvlbase;               // level-local edge base of this bin
  for (int i = t; i < 1024; i += 256) d[i] = 0;
  __syncthreads();
  for (int e = e0g + t; e < e1g; e += 256)
    atomicAdd(&d[p.pairs[e] >> 17], 1);
  __syncthreads();
  int a0 = d[4*t], a1 = d[4*t+1], a2 = d[4*t+2], a3 = d[4*t+3];
  int ts = a0 + a1 + a2 + a3;
  sd[t] = ts;
  __syncthreads();
  for (int off = 1; off < 256; off <<= 1) {
    int x = sd[t];
    if (t >= off) x += sd[t - off];
    __syncthreads();
    sd[t] = x;
    __syncthreads();
  }
  int c0 = e0 + sd[t] - ts;             // level-local exclusive prefix
  int c1 = c0 + a0, c2 = c1 + a1, c3 = c2 + a2;
  int* rp = p.rp[l];
  *(int4*)(rp + lb * 1024 + 4 * t) = make_int4(c0, c1, c2, c3);
  if (t == 0 && lb == cNB[l] - 1) rp[cNN[l]] = cNE[l];
  d[4*t] = c0; d[4*t+1] = c1; d[4*t+2] = c2; d[4*t+3] = c3;   // cursors
  __syncthreads();
  int* col = p.col[l];
  for (int e = e0g + t; e < e1g; e += 256) {
    int pk = p.pairs[e];
    int slot = atomicAdd(&d[pk >> 17], 1);
    col[slot] = pk & 0x1FFFF;
  }
}

// ---------------- GEMM: out = act(in @ W + bias), block-uniform 16-col groups ----------------
template <int KIN, int KOUT, bool ELU>
__global__ void __launch_bounds__(256) k_gemm(const float* __restrict__ in,
                                              const float* __restrict__ W,
                                              const float* __restrict__ bias,
                                              float* __restrict__ out, int n) {
  int r = blockIdx.x * 256 + threadIdx.x;
  int c0 = blockIdx.y * 16;
  float acc[16];
#pragma unroll
  for (int i = 0; i < 16; i++) acc[i] = bias ? bias[c0 + i] : 0.f;
  const float* row = in + (size_t)r * KIN;
  for (int k = 0; k < KIN; k += 4) {
    float4 a = *(const float4*)(row + k);
    const float* ap = (const float*)&a;
#pragma unroll
    for (int kk = 0; kk < 4; kk++) {
      float av = ap[kk];
#pragma unroll
      for (int i = 0; i < 16; i++) acc[i] += av * W[(k + kk) * KOUT + c0 + i];
    }
  }
  float* orow = out + (size_t)r * KOUT + c0;
#pragma unroll
  for (int i = 0; i < 16; i++) {
    float v = acc[i];
    if (ELU) v = v > 0.f ? v : expm1f(v);
    orow[i] = v;
  }
}

// ---------------- f = elu(h + CSR-gather-sum(hW)), float4 per thread ----------------
__global__ void k_agg_elu4(const float* __restrict__ h, const float* __restrict__ hW,
                           const int* __restrict__ rp, const int* __restrict__ col,
                           float* __restrict__ f, int n) {
  int gid = blockIdx.x * blockDim.x + threadIdx.x;
  if (gid >= n * (HID/4)) return;
  int v = gid / (HID/4);
  int c4 = (gid - v * (HID/4)) * 4;
  int e0 = rp[v], e1 = rp[v + 1];
  float4 s = *(const float4*)(h + (size_t)v*HID + c4);
  float* sp = (float*)&s;
  for (int e = e0; e < e1; e++) {
    int j = col[e];
    float4 x = *(const float4*)(hW + (size_t)j*HID + c4);
    sp[0] += x.x; sp[1] += x.y; sp[2] += x.z; sp[3] += x.w;
  }
#pragma unroll
  for (int i = 0; i < 4; i++) sp[i] = eluf(sp[i]);
  *(float4*)(f + (size_t)v*HID + c4) = s;
}

// ---------------- dst[v] = sum over CSR of src[j], src = (j<half ? top : old) ----------------
__global__ void k_prop4(const float* __restrict__ top, const float* __restrict__ oldb,
                        int half, const int* __restrict__ rp, const int* __restrict__ col,
                        float* __restrict__ dst, int n) {
  int gid = blockIdx.x * blockDim.x + threadIdx.x;
  if (gid >= n * (HID/4)) return;
  int v = gid / (HID/4);
  int c4 = (gid - v * (HID/4)) * 4;
  int e0 = rp[v], e1 = rp[v + 1];
  float4 s = {0,0,0,0};
  float* sp = (float*)&s;
  for (int e = e0; e < e1; e++) {
    int j = col[e];
    const float* src = (j < half) ? top : oldb;
    float4 x = *(const float4*)(src + (size_t)j*HID + c4);
    sp[0] += x.x; sp[1] += x.y; sp[2] += x.z; sp[3] += x.w;
  }
  *(float4*)(dst + (size_t)v*HID + c4) = s;
}

// ---------------- finalize bn2 (from partials) and fold into Wc ----------------
__global__ void k_fin_bn2(const float* __restrict__ pacc, int npart,
                          const float* __restrict__ g, const float* __restrict__ b,
                          const float* __restrict__ Wc, float* __restrict__ wcp) {
  __shared__ float sc[64], sh[64];
  int t = threadIdx.x; // 64 threads
  float s = 0.f, q = 0.f;
  for (int p = 0; p < npart; p++) {
    s += pacc[p * 128 + t];
    q += pacc[p * 128 + 64 + t];
  }
  float invn = 1.f / (float)cN0;
  float m = s * invn;
  float v = q * invn - m * m;
  float scv = g[t] * rsqrtf(v + 1e-5f);
  sc[t] = scv;
  sh[t] = b[t] - m * scv;
  __syncthreads();
  for (int i = t; i < 64 * 13; i += 64) { int c = i / 13; wcp[i] = sc[c] * Wc[i]; }
  if (t < 13) {
    float acc13 = 0.f;
    for (int c = 0; c < 64; c++) acc13 += sh[c] * Wc[c*13 + t];
    wcp[64*13 + t] = acc13;
  }
}

// ---------------- final: out = bn2(x3) @ Wc  == x3 @ Wc' + bias13 ----------------
__global__ void k_final(const float* __restrict__ x3, const float* __restrict__ wcp,
                        float* __restrict__ out) {
  __shared__ float Wl[64*13 + 13];
  for (int i = threadIdx.x; i < 64*13 + 13; i += blockDim.x) Wl[i] = wcp[i];
  __syncthreads();
  int gid = blockIdx.x * blockDim.x + threadIdx.x; // exactly N0*13
  int r = gid / 13, o = gid - r * 13;
  const float* row = x3 + (size_t)r * 64;
  float s = Wl[64*13 + o];
#pragma unroll
  for (int c = 0; c < 64; c++) s += row[c] * Wl[c*13 + o];
  out[gid] = s;
}

// ===========================================================================
extern "C" void kernel_launch(void* const* d_in, const int* in_sizes, int n_in,
                              void* d_out, int out_size, void* d_ws, size_t ws_size,
                              hipStream_t stream) {
  const float* feat   = (const float*)d_in[0];
  const float* bn1_g  = (const float*)d_in[1];
  const float* bn1_b  = (const float*)d_in[2];
  const float* W_emb  = (const float*)d_in[3];
  const float* embn_g = (const float*)d_in[4];
  const float* embn_b = (const float*)d_in[5];
  const float* W_msg  = (const float*)d_in[6];
  const float* W1 = (const float*)d_in[7];
  const float* b1 = (const float*)d_in[8];
  const float* W2 = (const float*)d_in[9];
  const float* b2 = (const float*)d_in[10];
  const float* W3 = (const float*)d_in[11];
  const float* b3 = (const float*)d_in[12];
  const float* bn2_g = (const float*)d_in[13];
  const float* bn2_b = (const float*)d_in[14];
  const float* Wc    = (const float*)d_in[15];

  const int NNODE[4] = {131072, 65536, 32768, 16384};
  const int NEDGE[4] = {917504, 458752, 229376, 114688};
  const int N = cN0;
  const int SBLK = 256;   // colstats partial blocks
  const int BN1B = 64;    // bn1 partial blocks

  // ---- workspace arena (256B-aligned) ----
  size_t off = 0;
  char* base = (char*)d_ws;
  auto af = [&](size_t nf) -> float* { float* p = (float*)(base + off); off += ((nf*4 + 255) & ~(size_t)255); return p; };
  auto ai = [&](size_t ni) -> int*   { int*   p = (int*)  (base + off); off += ((ni*4 + 255) & ~(size_t)255); return p; };

  size_t zero_start = off;
  int* cnt = ai(NBINS * REPS);          // zeroed each launch (15KB)
  size_t zero_end = off;
  int* bstart = ai(NBINS * REPS + 1);
  int* bcur   = ai(NBINS * REPS);
  int* pairs  = ai(NEDGE_TOT);

  float* pacc1 = af((size_t)BN1B * 12);
  float* pacce = af((size_t)SBLK * 160);
  float* pacc2 = af((size_t)SBLK * 128);
  float* ss1 = af(12);
  float* sse = af(160);
  float* wcp = af(64*13 + 13);
  int* rp[4];   for (int l = 0; l < 4; l++) rp[l]   = ai(NNODE[l] + 1);
  int* col[4];  for (int l = 0; l < 4; l++) col[l]  = ai(NEDGE[l]);

  float* t_h0 = af((size_t)N * HID);     // t -> h0 in place; later hud0 ping (H0P)
  float* hWb  = af((size_t)N * HID);     // hW per level; later hud0 pong (H0Q)
  float* f[4];
  f[0] = af((size_t)NNODE[0] * HID);
  f[1] = af((size_t)NNODE[1] * HID);
  f[2] = af((size_t)NNODE[2] * HID);
  f[3] = af((size_t)NNODE[3] * HID);
  float* h1a = af((size_t)NNODE[1] * HID);
  float* h1b = af((size_t)NNODE[1] * HID);
  float* h2a = af((size_t)NNODE[2] * HID);
  float* h2b = af((size_t)NNODE[2] * HID);
  float* h3  = af((size_t)NNODE[3] * HID);

  float* x1 = f[0];           // N*64 fits in f0's N*80
  float* x2 = f[1];           // N*64 fits in f1+f2+f3 span
  float* x3 = f[0];
  (void)ws_size; (void)in_sizes; (void)n_in; (void)out_size;

  // ---- zero only the (bin,rep) counters ----
  hipMemsetAsync(base + zero_start, 0, zero_end - zero_start, stream);

  // ---- bn1 -> scale/shift; embed; embn -> scale/shift; relu ----
  k_bn1_stats<<<BN1B, 256, 0, stream>>>(feat, pacc1);
  k_finalize<<<1, 64, 0, stream>>>(pacc1, BN1B, bn1_g, bn1_b, ss1, 6, 1.f / N);
  k_emb4<<<(N * (HID/4)) / 256, 256, 0, stream>>>(feat, W_emb, ss1, t_h0);
  k_colstats<<<SBLK, 320, 2*80*4, stream>>>(t_h0, N, 80, pacce);
  k_finalize<<<1, 128, 0, stream>>>(pacce, SBLK, embn_g, embn_b, sse, 80, 1.f / N);
  k_scale_relu4<<<(N * (HID/4)) / 256, 256, 0, stream>>>(t_h0, sse, N * (HID/4));

  // ---- binned CSR build, all levels batched: 4 launches ----
  BinP bp;
  for (int l = 0; l < 4; l++) {
    bp.ii[l] = (const int*)d_in[16 + 2*l];
    bp.jj[l] = (const int*)d_in[17 + 2*l];
    bp.rp[l] = rp[l]; bp.col[l] = col[l];
  }
  bp.cnt = cnt; bp.bstart = bstart; bp.bcur = bcur; bp.pairs = pairs;
  k_binA<<<NEDGE_TOT / BIN_CHUNK, 256, 0, stream>>>(bp);
  k_binScan<<<1, 256, 0, stream>>>(bp);
  k_binB<<<NEDGE_TOT / BIN_CHUNK, 256, 0, stream>>>(bp);
  k_binCSR<<<NBINS, 256, 0, stream>>>(bp);

  // ---- features per level: hW = h @ W_msg[l]; f = elu(h + csr_sum(hW)) ----
  const float* hin = t_h0;
  for (int l = 0; l < 4; l++) {
    int n = NNODE[l];
    dim3 g(n / 256, HID / 16);
    k_gemm<80, 80, false><<<g, 256, 0, stream>>>(hin, W_msg + (size_t)l * HID * HID, nullptr, hWb, n);
    k_agg_elu4<<<(n * (HID/4)) / 256, 256, 0, stream>>>(hin, hWb, rp[l], col[l], f[l], n);
    hin = f[l];
  }

  // ---- propagation: 10 unrolled segment-sums with conditional-source mix ----
  float* H0P = t_h0;  // h0 dead after features phase
  float* H0Q = hWb;   // hW dead after features phase
  const int B = 256;
  // l=0
  k_prop4<<<(NNODE[0]*(HID/4))/B, B, 0, stream>>>(f[0], f[0], NNODE[0], rp[0], col[0], H0P, NNODE[0]);
  // l=1
  k_prop4<<<(NNODE[1]*(HID/4))/B, B, 0, stream>>>(f[1], f[1], NNODE[1], rp[1], col[1], h1a, NNODE[1]);
  k_prop4<<<(NNODE[0]*(HID/4))/B, B, 0, stream>>>(h1a, H0P, 65536, rp[0], col[0], H0Q, NNODE[0]);
  // l=2
  k_prop4<<<(NNODE[2]*(HID/4))/B, B, 0, stream>>>(f[2], f[2], NNODE[2], rp[2], col[2], h2a, NNODE[2]);
  k_prop4<<<(NNODE[1]*(HID/4))/B, B, 0, stream>>>(h2a, h1a, 32768, rp[1], col[1], h1b, NNODE[1]);
  k_prop4<<<(NNODE[0]*(HID/4))/B, B, 0, stream>>>(h1b, H0Q, 65536, rp[0], col[0], H0P, NNODE[0]);
  // l=3
  k_prop4<<<(NNODE[3]*(HID/4))/B, B, 0, stream>>>(f[3], f[3], NNODE[3], rp[3], col[3], h3, NNODE[3]);
  k_prop4<<<(NNODE[2]*(HID/4))/B, B, 0, stream>>>(h3, h2a, 16384, rp[2], col[2], h2b, NNODE[2]);
  k_prop4<<<(NNODE[1]*(HID/4))/B, B, 0, stream>>>(h2b, h1b, 32768, rp[1], col[1], h1a, NNODE[1]);
  k_prop4<<<(NNODE[0]*(HID/4))/B, B, 0, stream>>>(h1a, H0P, 65536, rp[0], col[0], H0Q, NNODE[0]);
  // final h_up_down == H0Q

  // ---- MLP head + bn2 folded into Wc ----
  k_gemm<80, 64, true><<<dim3(N/256, 4), 256, 0, stream>>>(H0Q, W1, b1, x1, N);
  k_gemm<64, 64, true><<<dim3(N/256, 4), 256, 0, stream>>>(x1, W2, b2, x2, N);
  k_gemm<64, 64, true><<<dim3(N/256, 4), 256, 0, stream>>>(x2, W3, b3, x3, N);
  k_colstats<<<SBLK, 256, 2*64*4, stream>>>(x3, N, 64, pacc2);
  k_fin_bn2<<<1, 64, 0, stream>>>(pacc2, SBLK, bn2_g, bn2_b, Wc, wcp);
  k_final<<<(N * 13) / 256, 256, 0, stream>>>(x3, wcp, (float*)d_out);
}

// Round 2
// 1228.404 us; speedup vs baseline: 1.1273x; 1.1273x over previous
//
#include <hip/hip_runtime.h>
#include <math.h>

// ---------------------------------------------------------------------------
// FancyNet: 4-level hierarchical GNN + MLP head on MI355X.
//   * hW = h @ W_msg per-node (gather commutes with matmul) -> 7x less GEMM
//   * up_l == arange(N_l/2) => downsample = first-half rows; ".at[up].set(hud)"
//     = conditional-source read (j<half ? top : old)
//   * propagation unrolled to 10 prop kernels with ping-pong buffers
//   * BN folds to scale/shift; bn2 folded into Wc' + bias13
//   * R1 fix: NO contended global float atomics (stats via block partials).
//   * R2 lesson: global atomicAdd-with-return cursors (16 reps/bin) serialize
//     ~450 deep at remote-XCD latency -> k_binB was 190us, latency-bound
//     (370 GB/s, VALUBusy 0.45%). Write-side ping-pong: 16 WGs interleaving
//     appends per segment -> 62MB write-backs for 6.9MB payload.
//   * R3 fix: deterministic two-level counting sort. Chunks are level-exact
//     (448/224/112/56 WGs), so per-WG histograms are reproducible:
//       binA: LDS hist -> hist[wg][240] coalesced (no global atomics)
//       binT: per-bin scan over WGs -> offs[b][wg] + total[b]
//       binScan2: scan totals -> base[241]
//       binB: LDS cursors = base[b]+offs[b][wg]; per-edge LDS atomic + store.
//     Each (bin,wg) mini-segment ~1 cache line written by exactly one WG ->
//     ~1x write amplification, zero global atomics, no memset needed.
// ---------------------------------------------------------------------------

#define HID 80
constexpr int cN0 = 131072;

__device__ __forceinline__ float eluf(float x) { return x > 0.f ? x : expm1f(x); }

// ---------------- bn1 stats (6 cols): 2 rows/thread as 3x float4, block partials ----------------
__global__ void k_bn1_stats(const float* __restrict__ feat, float* __restrict__ pacc) {
  float s[6] = {0,0,0,0,0,0}, q[6] = {0,0,0,0,0,0};
  int idx = blockIdx.x * blockDim.x + threadIdx.x;
  int stride = gridDim.x * blockDim.x;
  for (int r2 = idx; r2 < cN0 / 2; r2 += stride) {
    const float4* p = (const float4*)(feat + (size_t)r2 * 12);
    float4 a = p[0], b = p[1], c = p[2];
    s[0] += a.x + b.z;  q[0] += a.x*a.x + b.z*b.z;
    s[1] += a.y + b.w;  q[1] += a.y*a.y + b.w*b.w;
    s[2] += a.z + c.x;  q[2] += a.z*a.z + c.x*c.x;
    s[3] += a.w + c.y;  q[3] += a.w*a.w + c.y*c.y;
    s[4] += b.x + c.z;  q[4] += b.x*b.x + c.z*c.z;
    s[5] += b.y + c.w;  q[5] += b.y*b.y + c.w*c.w;
  }
#pragma unroll
  for (int k = 0; k < 6; k++) {
    for (int off = 32; off; off >>= 1) {
      s[k] += __shfl_down(s[k], off, 64);
      q[k] += __shfl_down(q[k], off, 64);
    }
  }
  __shared__ float ls[4][12];
  int wid = threadIdx.x >> 6;
  if ((threadIdx.x & 63) == 0) {
#pragma unroll
    for (int k = 0; k < 6; k++) { ls[wid][k] = s[k]; ls[wid][6 + k] = q[k]; }
  }
  __syncthreads();
  if (threadIdx.x < 12) {
    pacc[blockIdx.x * 12 + threadIdx.x] =
        ls[0][threadIdx.x] + ls[1][threadIdx.x] + ls[2][threadIdx.x] + ls[3][threadIdx.x];
  }
}

// ---------------- finalize per-channel scale/shift from npart block partials ----------------
__global__ void k_finalize(const float* __restrict__ pacc, int npart,
                           const float* __restrict__ g, const float* __restrict__ b,
                           float* __restrict__ ss, int ncols, float inv_n) {
  int c = threadIdx.x;
  if (c >= ncols) return;
  float s = 0.f, q = 0.f;
  for (int p = 0; p < npart; p++) {
    s += pacc[p * 2 * ncols + c];
    q += pacc[p * 2 * ncols + ncols + c];
  }
  float m = s * inv_n;
  float v = q * inv_n - m * m;
  float sc = g[c] * rsqrtf(v + 1e-5f);
  ss[c] = sc;
  ss[ncols + c] = b[c] - m * sc;
}

// ---------------- embedding: t = bn1(feat) @ W_emb  (6 -> 80) ----------------
__global__ void k_emb4(const float* __restrict__ feat, const float* __restrict__ Wemb,
                       const float* __restrict__ ss, float* __restrict__ t) {
  __shared__ float Wl[6 * HID];
  __shared__ float sc[12];
  for (int i = threadIdx.x; i < 6 * HID; i += blockDim.x) Wl[i] = Wemb[i];
  if (threadIdx.x < 12) sc[threadIdx.x] = ss[threadIdx.x];
  __syncthreads();
  int gid = blockIdx.x * blockDim.x + threadIdx.x;
  if (gid >= cN0 * (HID/4)) return;
  int r = gid / (HID/4);
  int c4 = (gid - r * (HID/4)) * 4;
  float a[6];
#pragma unroll
  for (int k = 0; k < 6; k++) a[k] = feat[r*6 + k] * sc[k] + sc[6 + k];
  float4 o;
  float* op = (float*)&o;
#pragma unroll
  for (int i = 0; i < 4; i++) {
    float v = 0.f;
#pragma unroll
    for (int k = 0; k < 6; k++) v += a[k] * Wl[k*HID + c4 + i];
    op[i] = v;
  }
  *(float4*)(t + (size_t)r*HID + c4) = o;
}

// ---------------- column stats -> per-block partials (LDS atomics only) ----------------
__global__ void k_colstats(const float* __restrict__ x, int nrows, int ncols,
                           float* __restrict__ pacc) {
  extern __shared__ float ls[]; // 2*ncols
  int c = threadIdx.x % ncols;
  int sub = threadIdx.x / ncols;
  int rows_per = blockDim.x / ncols;
  for (int i = threadIdx.x; i < 2*ncols; i += blockDim.x) ls[i] = 0.f;
  __syncthreads();
  float s = 0.f, q = 0.f;
  for (int r = blockIdx.x * rows_per + sub; r < nrows; r += gridDim.x * rows_per) {
    float v = x[(size_t)r * ncols + c];
    s += v; q += v*v;
  }
  atomicAdd(&ls[c], s);
  atomicAdd(&ls[ncols + c], q);
  __syncthreads();
  for (int i = threadIdx.x; i < 2*ncols; i += blockDim.x)
    pacc[blockIdx.x * 2 * ncols + i] = ls[i];
}

// ---------------- in-place scale+shift+relu over 80-col matrix ----------------
__global__ void k_scale_relu4(float* __restrict__ x, const float* __restrict__ ss, int ntot4) {
  int gid = blockIdx.x * blockDim.x + threadIdx.x;
  if (gid >= ntot4) return;
  int r = gid / (HID/4);
  int c4 = (gid - r * (HID/4)) * 4;
  float4 t = *(float4*)(x + (size_t)r*HID + c4);
  float* tp = (float*)&t;
#pragma unroll
  for (int i = 0; i < 4; i++) {
    float v = tp[i] * ss[c4 + i] + ss[HID + c4 + i];
    tp[i] = v > 0.f ? v : 0.f;
  }
  *(float4*)(x + (size_t)r*HID + c4) = t;
}

// ---------------- binned CSR build (deterministic, atomic-free scatter) ----------------
// Bins: 1024 dst nodes each. Level bin counts {128,64,32,16} -> 240 bins total.
#define NBINS 240
#define NEDGE_TOT 1720320
#define BIN_CHUNK 2048   // edges per WG; 1720320/2048 = 840 WGs, level-exact splits
#define NWG 840

struct BinP {
  const int* ii[4]; const int* jj[4];
  int* hist;    // [NWG][NBINS] per-WG bin histograms
  int* offs;    // [NBINS][NWG] exclusive WG-prefix within bin
  int* total;   // [NBINS]
  int* base;    // [NBINS+1] exclusive scan of totals
  int* pairs;   // [NEDGE_TOT] packed (i_local<<17 | j), bin-grouped
  int* rp[4]; int* col[4];
};

__device__ __forceinline__ int edge_level(int gid, int& el) {
  if (gid < 917504)  { el = gid;           return 0; }
  if (gid < 1376256) { el = gid - 917504;  return 1; }
  if (gid < 1605632) { el = gid - 1376256; return 2; }
  el = gid - 1605632; return 3;
}
__device__ __forceinline__ int blk_level(int b, int& lb) {
  if (b < 128) { lb = b;       return 0; }
  if (b < 192) { lb = b - 128; return 1; }
  if (b < 224) { lb = b - 192; return 2; }
  lb = b - 224; return 3;
}
__constant__ const int cNN[4] = {131072, 65536, 32768, 16384};
__constant__ const int cNE[4] = {917504, 458752, 229376, 114688};
__constant__ const int cNB[4] = {128, 64, 32, 16};
__constant__ const int cLB[4] = {0, 128, 192, 224};   // first bin of each level

// Pass A: per-WG LDS histogram over 240 bins -> hist[wg][b] (coalesced write).
__global__ void k_binA(BinP p) {
  __shared__ int h[NBINS];
  for (int i = threadIdx.x; i < NBINS; i += 256) h[i] = 0;
  __syncthreads();
  int ebase = blockIdx.x * BIN_CHUNK;
#pragma unroll
  for (int it = 0; it < BIN_CHUNK / 256; it++) {
    int e = ebase + it * 256 + threadIdx.x;
    int el; int l = edge_level(e, el);
    atomicAdd(&h[cLB[l] + (p.ii[l][el] >> 10)], 1);
  }
  __syncthreads();
  for (int b = threadIdx.x; b < NBINS; b += 256)
    p.hist[blockIdx.x * NBINS + b] = h[b];
}

// Pass T: one WG per bin. Exclusive scan of hist[:,b] over the 840 WGs.
// Strided reads hit the L2/L3-resident 806KB hist array; writes coalesced.
__global__ void k_binT(BinP p) {
  __shared__ int sd[256];
  int b = blockIdx.x;
  int t = threadIdx.x;
  int carry = 0;
  for (int r = 0; r < 4; r++) {
    int idx = r * 256 + t;
    int v = (idx < NWG) ? p.hist[idx * NBINS + b] : 0;
    sd[t] = v;
    __syncthreads();
    for (int off = 1; off < 256; off <<= 1) {
      int x = sd[t];
      if (t >= off) x += sd[t - off];
      __syncthreads();
      sd[t] = x;
      __syncthreads();
    }
    if (idx < NWG) p.offs[b * NWG + idx] = carry + sd[t] - v;  // exclusive
    carry += sd[255];
    __syncthreads();
  }
  if (t == 0) p.total[b] = carry;
}

// Pass S: 1 WG, exclusive scan of 240 bin totals -> base[241].
__global__ void k_binScan2(BinP p) {
  __shared__ int sd[256];
  int t = threadIdx.x;
  int v = (t < NBINS) ? p.total[t] : 0;
  sd[t] = v;
  __syncthreads();
  for (int off = 1; off < 256; off <<= 1) {
    int x = sd[t];
    if (t >= off) x += sd[t - off];
    __syncthreads();
    sd[t] = x;
    __syncthreads();
  }
  if (t < NBINS) p.base[t] = sd[t] - v;
  if (t == NBINS - 1) p.base[NBINS] = sd[t];
}

// Pass B: deterministic scatter. LDS cursors seeded with base[b]+offs[b][wg];
// per-edge LDS atomicAdd (avg ~8-16 deep) + plain global store. Each (bin,wg)
// mini-segment (~1 line) is written by exactly one WG -> lines merge in L2.
__global__ void k_binB(BinP p) {
  __shared__ int cur[NBINS];
  int wg = blockIdx.x;
  for (int b = threadIdx.x; b < NBINS; b += 256)
    cur[b] = p.base[b] + p.offs[b * NWG + wg];
  __syncthreads();
  int ebase = wg * BIN_CHUNK;
#pragma unroll
  for (int it = 0; it < BIN_CHUNK / 256; it++) {
    int e = ebase + it * 256 + threadIdx.x;
    int el; int l = edge_level(e, el);
    int i = p.ii[l][el], j = p.jj[l][el];
    int b = cLB[l] + (i >> 10);
    int gpos = atomicAdd(&cur[b], 1);
    p.pairs[gpos] = ((i & 1023) << 17) | j;   // j < 131072 -> 17 bits
  }
}

// Pass D: one WG per bin. LDS degree count + scan -> rp (coalesced int4),
// LDS cursors -> col scatter confined to this bin's contiguous ~28KB region.
__global__ void __launch_bounds__(256) k_binCSR(BinP p) {
  __shared__ int d[1024];
  __shared__ int sd[256];
  int lb; int l = blk_level(blockIdx.x, lb);
  int t = threadIdx.x;
  int e0g = p.base[blockIdx.x];
  int e1g = p.base[blockIdx.x + 1];
  int lvlbase = p.base[cLB[l]];
  int e0 = e0g - lvlbase;               // level-local edge base of this bin
  for (int i = t; i < 1024; i += 256) d[i] = 0;
  __syncthreads();
  for (int e = e0g + t; e < e1g; e += 256)
    atomicAdd(&d[p.pairs[e] >> 17], 1);
  __syncthreads();
  int a0 = d[4*t], a1 = d[4*t+1], a2 = d[4*t+2], a3 = d[4*t+3];
  int ts = a0 + a1 + a2 + a3;
  sd[t] = ts;
  __syncthreads();
  for (int off = 1; off < 256; off <<= 1) {
    int x = sd[t];
    if (t >= off) x += sd[t - off];
    __syncthreads();
    sd[t] = x;
    __syncthreads();
  }
  int c0 = e0 + sd[t] - ts;             // level-local exclusive prefix
  int c1 = c0 + a0, c2 = c1 + a1, c3 = c2 + a2;
  int* rp = p.rp[l];
  *(int4*)(rp + lb * 1024 + 4 * t) = make_int4(c0, c1, c2, c3);
  if (t == 0 && lb == cNB[l] - 1) rp[cNN[l]] = cNE[l];
  d[4*t] = c0; d[4*t+1] = c1; d[4*t+2] = c2; d[4*t+3] = c3;   // cursors
  __syncthreads();
  int* col = p.col[l];
  for (int e = e0g + t; e < e1g; e += 256) {
    int pk = p.pairs[e];
    int slot = atomicAdd(&d[pk >> 17], 1);
    col[slot] = pk & 0x1FFFF;
  }
}

// ---------------- GEMM: out = act(in @ W + bias), block-uniform 16-col groups ----------------
template <int KIN, int KOUT, bool ELU>
__global__ void __launch_bounds__(256) k_gemm(const float* __restrict__ in,
                                              const float* __restrict__ W,
                                              const float* __restrict__ bias,
                                              float* __restrict__ out, int n) {
  int r = blockIdx.x * 256 + threadIdx.x;
  int c0 = blockIdx.y * 16;
  float acc[16];
#pragma unroll
  for (int i = 0; i < 16; i++) acc[i] = bias ? bias[c0 + i] : 0.f;
  const float* row = in + (size_t)r * KIN;
  for (int k = 0; k < KIN; k += 4) {
    float4 a = *(const float4*)(row + k);
    const float* ap = (const float*)&a;
#pragma unroll
    for (int kk = 0; kk < 4; kk++) {
      float av = ap[kk];
#pragma unroll
      for (int i = 0; i < 16; i++) acc[i] += av * W[(k + kk) * KOUT + c0 + i];
    }
  }
  float* orow = out + (size_t)r * KOUT + c0;
#pragma unroll
  for (int i = 0; i < 16; i++) {
    float v = acc[i];
    if (ELU) v = v > 0.f ? v : expm1f(v);
    orow[i] = v;
  }
}

// ---------------- f = elu(h + CSR-gather-sum(hW)), float4 per thread ----------------
__global__ void k_agg_elu4(const float* __restrict__ h, const float* __restrict__ hW,
                           const int* __restrict__ rp, const int* __restrict__ col,
                           float* __restrict__ f, int n) {
  int gid = blockIdx.x * blockDim.x + threadIdx.x;
  if (gid >= n * (HID/4)) return;
  int v = gid / (HID/4);
  int c4 = (gid - v * (HID/4)) * 4;
  int e0 = rp[v], e1 = rp[v + 1];
  float4 s = *(const float4*)(h + (size_t)v*HID + c4);
  float* sp = (float*)&s;
  for (int e = e0; e < e1; e++) {
    int j = col[e];
    float4 x = *(const float4*)(hW + (size_t)j*HID + c4);
    sp[0] += x.x; sp[1] += x.y; sp[2] += x.z; sp[3] += x.w;
  }
#pragma unroll
  for (int i = 0; i < 4; i++) sp[i] = eluf(sp[i]);
  *(float4*)(f + (size_t)v*HID + c4) = s;
}

// ---------------- dst[v] = sum over CSR of src[j], src = (j<half ? top : old) ----------------
__global__ void k_prop4(const float* __restrict__ top, const float* __restrict__ oldb,
                        int half, const int* __restrict__ rp, const int* __restrict__ col,
                        float* __restrict__ dst, int n) {
  int gid = blockIdx.x * blockDim.x + threadIdx.x;
  if (gid >= n * (HID/4)) return;
  int v = gid / (HID/4);
  int c4 = (gid - v * (HID/4)) * 4;
  int e0 = rp[v], e1 = rp[v + 1];
  float4 s = {0,0,0,0};
  float* sp = (float*)&s;
  for (int e = e0; e < e1; e++) {
    int j = col[e];
    const float* src = (j < half) ? top : oldb;
    float4 x = *(const float4*)(src + (size_t)j*HID + c4);
    sp[0] += x.x; sp[1] += x.y; sp[2] += x.z; sp[3] += x.w;
  }
  *(float4*)(dst + (size_t)v*HID + c4) = s;
}

// ---------------- finalize bn2 (from partials) and fold into Wc ----------------
__global__ void k_fin_bn2(const float* __restrict__ pacc, int npart,
                          const float* __restrict__ g, const float* __restrict__ b,
                          const float* __restrict__ Wc, float* __restrict__ wcp) {
  __shared__ float sc[64], sh[64];
  int t = threadIdx.x; // 64 threads
  float s = 0.f, q = 0.f;
  for (int p = 0; p < npart; p++) {
    s += pacc[p * 128 + t];
    q += pacc[p * 128 + 64 + t];
  }
  float invn = 1.f / (float)cN0;
  float m = s * invn;
  float v = q * invn - m * m;
  float scv = g[t] * rsqrtf(v + 1e-5f);
  sc[t] = scv;
  sh[t] = b[t] - m * scv;
  __syncthreads();
  for (int i = t; i < 64 * 13; i += 64) { int c = i / 13; wcp[i] = sc[c] * Wc[i]; }
  if (t < 13) {
    float acc13 = 0.f;
    for (int c = 0; c < 64; c++) acc13 += sh[c] * Wc[c*13 + t];
    wcp[64*13 + t] = acc13;
  }
}

// ---------------- final: out = bn2(x3) @ Wc  == x3 @ Wc' + bias13 ----------------
__global__ void k_final(const float* __restrict__ x3, const float* __restrict__ wcp,
                        float* __restrict__ out) {
  __shared__ float Wl[64*13 + 13];
  for (int i = threadIdx.x; i < 64*13 + 13; i += blockDim.x) Wl[i] = wcp[i];
  __syncthreads();
  int gid = blockIdx.x * blockDim.x + threadIdx.x; // exactly N0*13
  int r = gid / 13, o = gid - r * 13;
  const float* row = x3 + (size_t)r * 64;
  float s = Wl[64*13 + o];
#pragma unroll
  for (int c = 0; c < 64; c++) s += row[c] * Wl[c*13 + o];
  out[gid] = s;
}

// ===========================================================================
extern "C" void kernel_launch(void* const* d_in, const int* in_sizes, int n_in,
                              void* d_out, int out_size, void* d_ws, size_t ws_size,
                              hipStream_t stream) {
  const float* feat   = (const float*)d_in[0];
  const float* bn1_g  = (const float*)d_in[1];
  const float* bn1_b  = (const float*)d_in[2];
  const float* W_emb  = (const float*)d_in[3];
  const float* embn_g = (const float*)d_in[4];
  const float* embn_b = (const float*)d_in[5];
  const float* W_msg  = (const float*)d_in[6];
  const float* W1 = (const float*)d_in[7];
  const float* b1 = (const float*)d_in[8];
  const float* W2 = (const float*)d_in[9];
  const float* b2 = (const float*)d_in[10];
  const float* W3 = (const float*)d_in[11];
  const float* b3 = (const float*)d_in[12];
  const float* bn2_g = (const float*)d_in[13];
  const float* bn2_b = (const float*)d_in[14];
  const float* Wc    = (const float*)d_in[15];

  const int NNODE[4] = {131072, 65536, 32768, 16384};
  const int NEDGE[4] = {917504, 458752, 229376, 114688};
  const int N = cN0;
  const int SBLK = 256;   // colstats partial blocks
  const int BN1B = 64;    // bn1 partial blocks

  // ---- workspace arena (256B-aligned) ----
  size_t off = 0;
  char* base = (char*)d_ws;
  auto af = [&](size_t nf) -> float* { float* p = (float*)(base + off); off += ((nf*4 + 255) & ~(size_t)255); return p; };
  auto ai = [&](size_t ni) -> int*   { int*   p = (int*)  (base + off); off += ((ni*4 + 255) & ~(size_t)255); return p; };

  int* hist   = ai((size_t)NWG * NBINS);
  int* offs   = ai((size_t)NBINS * NWG);
  int* total  = ai(NBINS);
  int* bbase  = ai(NBINS + 1);
  int* pairs  = ai(NEDGE_TOT);

  float* pacc1 = af((size_t)BN1B * 12);
  float* pacce = af((size_t)SBLK * 160);
  float* pacc2 = af((size_t)SBLK * 128);
  float* ss1 = af(12);
  float* sse = af(160);
  float* wcp = af(64*13 + 13);
  int* rp[4];   for (int l = 0; l < 4; l++) rp[l]   = ai(NNODE[l] + 1);
  int* col[4];  for (int l = 0; l < 4; l++) col[l]  = ai(NEDGE[l]);

  float* t_h0 = af((size_t)N * HID);     // t -> h0 in place; later hud0 ping (H0P)
  float* hWb  = af((size_t)N * HID);     // hW per level; later hud0 pong (H0Q)
  float* f[4];
  f[0] = af((size_t)NNODE[0] * HID);
  f[1] = af((size_t)NNODE[1] * HID);
  f[2] = af((size_t)NNODE[2] * HID);
  f[3] = af((size_t)NNODE[3] * HID);
  float* h1a = af((size_t)NNODE[1] * HID);
  float* h1b = af((size_t)NNODE[1] * HID);
  float* h2a = af((size_t)NNODE[2] * HID);
  float* h2b = af((size_t)NNODE[2] * HID);
  float* h3  = af((size_t)NNODE[3] * HID);

  float* x1 = f[0];           // N*64 fits in f0's N*80
  float* x2 = f[1];           // N*64 fits in f1+f2+f3 span
  float* x3 = f[0];
  (void)ws_size; (void)in_sizes; (void)n_in; (void)out_size;

  // ---- bn1 -> scale/shift; embed; embn -> scale/shift; relu ----
  k_bn1_stats<<<BN1B, 256, 0, stream>>>(feat, pacc1);
  k_finalize<<<1, 64, 0, stream>>>(pacc1, BN1B, bn1_g, bn1_b, ss1, 6, 1.f / N);
  k_emb4<<<(N * (HID/4)) / 256, 256, 0, stream>>>(feat, W_emb, ss1, t_h0);
  k_colstats<<<SBLK, 320, 2*80*4, stream>>>(t_h0, N, 80, pacce);
  k_finalize<<<1, 128, 0, stream>>>(pacce, SBLK, embn_g, embn_b, sse, 80, 1.f / N);
  k_scale_relu4<<<(N * (HID/4)) / 256, 256, 0, stream>>>(t_h0, sse, N * (HID/4));

  // ---- binned CSR build, deterministic: 5 launches, no global atomics ----
  BinP bp;
  for (int l = 0; l < 4; l++) {
    bp.ii[l] = (const int*)d_in[16 + 2*l];
    bp.jj[l] = (const int*)d_in[17 + 2*l];
    bp.rp[l] = rp[l]; bp.col[l] = col[l];
  }
  bp.hist = hist; bp.offs = offs; bp.total = total; bp.base = bbase; bp.pairs = pairs;
  k_binA<<<NWG, 256, 0, stream>>>(bp);
  k_binT<<<NBINS, 256, 0, stream>>>(bp);
  k_binScan2<<<1, 256, 0, stream>>>(bp);
  k_binB<<<NWG, 256, 0, stream>>>(bp);
  k_binCSR<<<NBINS, 256, 0, stream>>>(bp);

  // ---- features per level: hW = h @ W_msg[l]; f = elu(h + csr_sum(hW)) ----
  const float* hin = t_h0;
  for (int l = 0; l < 4; l++) {
    int n = NNODE[l];
    dim3 g(n / 256, HID / 16);
    k_gemm<80, 80, false><<<g, 256, 0, stream>>>(hin, W_msg + (size_t)l * HID * HID, nullptr, hWb, n);
    k_agg_elu4<<<(n * (HID/4)) / 256, 256, 0, stream>>>(hin, hWb, rp[l], col[l], f[l], n);
    hin = f[l];
  }

  // ---- propagation: 10 unrolled segment-sums with conditional-source mix ----
  float* H0P = t_h0;  // h0 dead after features phase
  float* H0Q = hWb;   // hW dead after features phase
  const int B = 256;
  // l=0
  k_prop4<<<(NNODE[0]*(HID/4))/B, B, 0, stream>>>(f[0], f[0], NNODE[0], rp[0], col[0], H0P, NNODE[0]);
  // l=1
  k_prop4<<<(NNODE[1]*(HID/4))/B, B, 0, stream>>>(f[1], f[1], NNODE[1], rp[1], col[1], h1a, NNODE[1]);
  k_prop4<<<(NNODE[0]*(HID/4))/B, B, 0, stream>>>(h1a, H0P, 65536, rp[0], col[0], H0Q, NNODE[0]);
  // l=2
  k_prop4<<<(NNODE[2]*(HID/4))/B, B, 0, stream>>>(f[2], f[2], NNODE[2], rp[2], col[2], h2a, NNODE[2]);
  k_prop4<<<(NNODE[1]*(HID/4))/B, B, 0, stream>>>(h2a, h1a, 32768, rp[1], col[1], h1b, NNODE[1]);
  k_prop4<<<(NNODE[0]*(HID/4))/B, B, 0, stream>>>(h1b, H0Q, 65536, rp[0], col[0], H0P, NNODE[0]);
  // l=3
  k_prop4<<<(NNODE[3]*(HID/4))/B, B, 0, stream>>>(f[3], f[3], NNODE[3], rp[3], col[3], h3, NNODE[3]);
  k_prop4<<<(NNODE[2]*(HID/4))/B, B, 0, stream>>>(h3, h2a, 16384, rp[2], col[2], h2b, NNODE[2]);
  k_prop4<<<(NNODE[1]*(HID/4))/B, B, 0, stream>>>(h2b, h1b, 32768, rp[1], col[1], h1a, NNODE[1]);
  k_prop4<<<(NNODE[0]*(HID/4))/B, B, 0, stream>>>(h1a, H0P, 65536, rp[0], col[0], H0Q, NNODE[0]);
  // final h_up_down == H0Q

  // ---- MLP head + bn2 folded into Wc ----
  k_gemm<80, 64, true><<<dim3(N/256, 4), 256, 0, stream>>>(H0Q, W1, b1, x1, N);
  k_gemm<64, 64, true><<<dim3(N/256, 4), 256, 0, stream>>>(x1, W2, b2, x2, N);
  k_gemm<64, 64, true><<<dim3(N/256, 4), 256, 0, stream>>>(x2, W3, b3, x3, N);
  k_colstats<<<SBLK, 256, 2*64*4, stream>>>(x3, N, 64, pacc2);
  k_fin_bn2<<<1, 64, 0, stream>>>(pacc2, SBLK, bn2_g, bn2_b, Wc, wcp);
  k_final<<<(N * 13) / 256, 256, 0, stream>>>(x3, wcp, (float*)d_out);
}